// Round 1
// baseline (234.833 us; speedup 1.0000x reference)
//
#include <hip/hip_runtime.h>
#include <stdint.h>

// Problem constants (fixed by reference setup_inputs): B=4096, D=512, L=80
#define B_ROWS 4096
#define DIMS   512
#define NLAB   80
#define HALF_ROWS 2048
#define HCNT   8388608u   // B*B/2 = 2^23, threefry counter split point
#define NSEG   5

typedef unsigned long long u64;

__device__ __forceinline__ uint32_t rotl32(uint32_t x, uint32_t d) {
    return (x << d) | (x >> (32u - d));
}

// JAX threefry2x32 with key = (0, 42)  [jax.random.key(42) -> key_data (0,42)]
// Counter pair (c0, c1) = (p, p + HCNT); outputs o0 = bits[p], o1 = bits[p+HCNT].
__device__ __forceinline__ void tf2x32_key42(uint32_t c0, uint32_t c1,
                                             uint32_t& o0, uint32_t& o1) {
    const uint32_t ks0 = 0u;
    const uint32_t ks1 = 42u;
    const uint32_t ks2 = 0x1BD11BDAu ^ 0u ^ 42u;
    uint32_t x0 = c0 + ks0;
    uint32_t x1 = c1 + ks1;
#define TF_RND(r) { x0 += x1; x1 = rotl32(x1, (r)); x1 ^= x0; }
    TF_RND(13u) TF_RND(15u) TF_RND(26u) TF_RND(6u)
    x0 += ks1; x1 += ks2 + 1u;
    TF_RND(17u) TF_RND(29u) TF_RND(16u) TF_RND(24u)
    x0 += ks2; x1 += ks0 + 2u;
    TF_RND(13u) TF_RND(15u) TF_RND(26u) TF_RND(6u)
    x0 += ks0; x1 += ks1 + 3u;
    TF_RND(17u) TF_RND(29u) TF_RND(16u) TF_RND(24u)
    x0 += ks1; x1 += ks2 + 4u;
    TF_RND(13u) TF_RND(15u) TF_RND(26u) TF_RND(6u)
    x0 += ks2; x1 += ks0 + 5u;
#undef TF_RND
    o0 = x0; o1 = x1;
}

__device__ __forceinline__ u64 shflx64(u64 v, int m) {
    uint32_t lo = __shfl_xor((uint32_t)(v & 0xFFFFFFFFull), m, 64);
    uint32_t hi = __shfl_xor((uint32_t)(v >> 32), m, 64);
    return ((u64)hi << 32) | (u64)lo;
}

__device__ __forceinline__ u64 umax64(u64 a, u64 b) { return a > b ? a : b; }
__device__ __forceinline__ u64 umin64(u64 a, u64 b) { return a < b ? a : b; }

// keep sorted-descending top-5 (all keys globally distinct: low bits hold ~j)
__device__ __forceinline__ void top5_insert(u64* t, u64 k) {
    if (k > t[4]) {
        t[4] = k;
        u64 tmp;
        if (t[4] > t[3]) { tmp = t[3]; t[3] = t[4]; t[4] = tmp; }
        if (t[3] > t[2]) { tmp = t[2]; t[2] = t[3]; t[3] = tmp; }
        if (t[2] > t[1]) { tmp = t[1]; t[1] = t[2]; t[2] = tmp; }
        if (t[1] > t[0]) { tmp = t[0]; t[0] = t[1]; t[1] = tmp; }
    }
}

// merge two sorted-desc 5-lists, keep top-5 (register-only network):
// m_k = max over i+j=k+1 of min(A~_i, B~_j), A~_0 = +inf boundary terms
__device__ __forceinline__ void merge_top5(u64* A, const u64* Bv) {
    u64 a0=A[0],a1=A[1],a2=A[2],a3=A[3],a4=A[4];
    u64 b0=Bv[0],b1=Bv[1],b2=Bv[2],b3=Bv[3],b4=Bv[4];
    u64 m0 = umax64(a0, b0);
    u64 m1 = umax64(umax64(a1, b1), umin64(a0, b0));
    u64 m2 = umax64(umax64(a2, b2), umax64(umin64(a0, b1), umin64(a1, b0)));
    u64 m3 = umax64(umax64(a3, b3),
                    umax64(umax64(umin64(a0, b2), umin64(a1, b1)), umin64(a2, b0)));
    u64 m4 = umax64(umax64(a4, b4),
                    umax64(umax64(umin64(a0, b3), umin64(a1, b2)),
                           umax64(umin64(a2, b1), umin64(a3, b0))));
    A[0]=m0; A[1]=m1; A[2]=m2; A[3]=m3; A[4]=m4;
}

__device__ __forceinline__ uint32_t inter3(uint4 a, uint4 b) {
    return (uint32_t)(__popc(a.x & b.x) + __popc(a.y & b.y) + __popc(a.z & b.z));
}

// ---------------- kernels ----------------

__global__ __launch_bounds__(256) void pack_kernel(const int* __restrict__ labels,
                                                   uint4* __restrict__ packed) {
    int r = blockIdx.x * 256 + threadIdx.x;
    if (r >= B_ROWS) return;
    const int* row = labels + (size_t)r * NLAB;
    uint32_t w0 = 0, w1 = 0, w2 = 0;
#pragma unroll
    for (int l = 0; l < 32; ++l) w0 |= (row[l]      != 0 ? 1u : 0u) << l;
#pragma unroll
    for (int l = 0; l < 32; ++l) w1 |= (row[32 + l] != 0 ? 1u : 0u) << l;
#pragma unroll
    for (int l = 0; l < 16; ++l) w2 |= (row[64 + l] != 0 ? 1u : 0u) << l;
    uint32_t c = (uint32_t)(__popc(w0) + __popc(w1) + __popc(w2));
    packed[r] = make_uint4(w0, w1, w2, c);
}

__global__ __launch_bounds__(256) void norm_kernel(const float* __restrict__ x,
                                                   float* __restrict__ norms) {
    const int w = (int)((blockIdx.x * 256 + threadIdx.x) >> 6);
    const int lane = threadIdx.x & 63;
    if (w >= B_ROWS) return;
    const float* row = x + (size_t)w * DIMS;
    float ss = 0.f;
#pragma unroll
    for (int u = 0; u < DIMS / 64; ++u) { float v = row[lane + 64 * u]; ss += v * v; }
#pragma unroll
    for (int m = 1; m < 64; m <<= 1) ss += __shfl_xor(ss, m, 64);
    if (lane == 0) norms[w] = fmaxf(sqrtf(ss), 1e-12f);
}

__global__ __launch_bounds__(256) void main_kernel(const float* __restrict__ x,
                                                   const uint4* __restrict__ packed,
                                                   const float* __restrict__ norms,
                                                   float* __restrict__ acc) {
    __shared__ uint4 tab[B_ROWS];   // 64 KB label bitmask+count table
    const int tid = threadIdx.x;
#pragma unroll
    for (int k = 0; k < B_ROWS / 256; ++k) tab[tid + 256 * k] = packed[tid + 256 * k];
    __syncthreads();

    const int lane = tid & 63;
    const int wid  = tid >> 6;
    const int pr   = (int)blockIdx.x * 4 + wid;      // [0, 2048)
    const int r0   = pr, r1 = pr + HALF_ROWS;
    const uint4 m0 = tab[r0], m1 = tab[r1];
    const uint32_t base = (uint32_t)pr * (uint32_t)B_ROWS;

    // ---- pass 1: gumbel-argmax positive (argmax of bits>>9 among jacc>0.5) ----
    u64 best0 = 0ull, best1 = 0ull;
    for (int jb = 0; jb < B_ROWS; jb += 64) {
        const int j = jb + lane;
        const uint4 mj = tab[j];
        uint32_t o0, o1;
        tf2x32_key42(base + (uint32_t)j, base + (uint32_t)j + HCNT, o0, o1);
        const uint32_t ixor = 0xFFFFFFFFu ^ (uint32_t)j;
        {
            uint32_t it = inter3(m0, mj);
            float ja = (float)it / (float)(m0.w + mj.w - it);
            if (ja > 0.5f) {
                u64 key = ((u64)(o0 >> 9) << 32) | (u64)ixor;
                best0 = key > best0 ? key : best0;
            }
        }
        {
            uint32_t it = inter3(m1, mj);
            float ja = (float)it / (float)(m1.w + mj.w - it);
            if (ja > 0.5f) {
                u64 key = ((u64)(o1 >> 9) << 32) | (u64)ixor;
                best1 = key > best1 ? key : best1;
            }
        }
    }
#pragma unroll
    for (int m = 1; m < 64; m <<= 1) {
        u64 ob0 = shflx64(best0, m), ob1 = shflx64(best1, m);
        best0 = ob0 > best0 ? ob0 : best0;
        best1 = ob1 > best1 ? ob1 : best1;
    }
    const bool valid0 = best0 != 0ull, valid1 = best1 != 0ull;
    const int pos0 = valid0 ? (int)(0xFFFFFFFFu ^ (uint32_t)(best0 & 0xFFFFFFFFull)) : 0;
    const int pos1 = valid1 ? (int)(0xFFFFFFFFu ^ (uint32_t)(best1 & 0xFFFFFFFFull)) : 0;

    float pj0, pj1;
    {
        uint4 mp = tab[pos0];
        uint32_t it = inter3(m0, mp);
        pj0 = (float)it / (float)(m0.w + mp.w - it);
        mp = tab[pos1];
        it = inter3(m1, mp);
        pj1 = (float)it / (float)(m1.w + mp.w - it);
    }

    // ---- pass 2: top-5 negatives by (jacc desc, index asc), -inf filler ----
    u64 t0[5] = {0,0,0,0,0}, t1[5] = {0,0,0,0,0};
    for (int jb = 0; jb < B_ROWS; jb += 64) {
        const int j = jb + lane;
        const uint4 mj = tab[j];
        const uint32_t ixor = 0xFFFFFFFFu ^ (uint32_t)j;
        {
            uint32_t it = inter3(m0, mj);
            float ja = (float)it / (float)(m0.w + mj.w - it);
            // monotone key: jacc >= 0 -> bits|signbit ; not-a-negative -> -inf key
            uint32_t hi = (ja < pj0) ? (__float_as_uint(ja) | 0x80000000u) : 0x007FFFFFu;
            top5_insert(t0, ((u64)hi << 32) | (u64)ixor);
        }
        {
            uint32_t it = inter3(m1, mj);
            float ja = (float)it / (float)(m1.w + mj.w - it);
            uint32_t hi = (ja < pj1) ? (__float_as_uint(ja) | 0x80000000u) : 0x007FFFFFu;
            top5_insert(t1, ((u64)hi << 32) | (u64)ixor);
        }
    }
#pragma unroll
    for (int m = 1; m < 64; m <<= 1) {
        u64 o[5];
#pragma unroll
        for (int k = 0; k < 5; ++k) o[k] = shflx64(t0[k], m);
        merge_top5(t0, o);
#pragma unroll
        for (int k = 0; k < 5; ++k) o[k] = shflx64(t1[k], m);
        merge_top5(t1, o);
    }

    int tg0[6], tg1[6];
    tg0[0] = pos0; tg1[0] = pos1;
#pragma unroll
    for (int k = 0; k < 5; ++k) {
        tg0[k + 1] = (int)(0xFFFFFFFFu ^ (uint32_t)(t0[k] & 0xFFFFFFFFull));
        tg1[k + 1] = (int)(0xFFFFFFFFu ^ (uint32_t)(t1[k] & 0xFFFFFFFFull));
    }

    // ---- cosine sims at the 6 sampled indices per row (12 dots of length 512) ----
    const float* xr0 = x + (size_t)r0 * DIMS;
    const float* xr1 = x + (size_t)r1 * DIMS;
    float v0[8], v1[8];
#pragma unroll
    for (int u = 0; u < 8; ++u) { v0[u] = xr0[lane + 64 * u]; v1[u] = xr1[lane + 64 * u]; }
    float s0[6], s1[6];
#pragma unroll
    for (int q = 0; q < 6; ++q) {
        const float* p0 = x + (size_t)tg0[q] * DIMS;
        const float* p1 = x + (size_t)tg1[q] * DIMS;
        float a = 0.f, b = 0.f;
#pragma unroll
        for (int u = 0; u < 8; ++u) {
            a += v0[u] * p0[lane + 64 * u];
            b += v1[u] * p1[lane + 64 * u];
        }
#pragma unroll
        for (int m = 1; m < 64; m <<= 1) {
            a += __shfl_xor(a, m, 64);
            b += __shfl_xor(b, m, 64);
        }
        s0[q] = a; s1[q] = b;
    }

    if (lane == 0) {
        if (valid0) {
            const float nr = norms[r0];
            float sp = s0[0] / (nr * norms[tg0[0]]);
            float sen = 0.f;
#pragma unroll
            for (int k = 1; k < 6; ++k) sen += expf(s0[k] / (nr * norms[tg0[k]]));
            float ep = expf(sp);
            float loss = -logf(ep / (ep + sen));
            atomicAdd(&acc[0], loss);
            atomicAdd(&acc[1], 1.0f);
        }
        if (valid1) {
            const float nr = norms[r1];
            float sp = s1[0] / (nr * norms[tg1[0]]);
            float sen = 0.f;
#pragma unroll
            for (int k = 1; k < 6; ++k) sen += expf(s1[k] / (nr * norms[tg1[k]]));
            float ep = expf(sp);
            float loss = -logf(ep / (ep + sen));
            atomicAdd(&acc[0], loss);
            atomicAdd(&acc[1], 1.0f);
        }
    }
}

__global__ void final_kernel(const float* __restrict__ acc, float* __restrict__ out) {
    out[0] = acc[0] / acc[1];
}

extern "C" void kernel_launch(void* const* d_in, const int* in_sizes, int n_in,
                              void* d_out, int out_size, void* d_ws, size_t ws_size,
                              hipStream_t stream) {
    const float* x      = (const float*)d_in[0];
    const int*   labels = (const int*)d_in[1];
    float* out = (float*)d_out;

    char* ws = (char*)d_ws;
    float* acc    = (float*)ws;                  // 16 B (2 floats used)
    float* norms  = (float*)(ws + 16);           // 4096 * 4 B
    uint4* packed = (uint4*)(ws + 16 + 16384);   // 4096 * 16 B

    hipMemsetAsync(acc, 0, 16, stream);
    hipLaunchKernelGGL(pack_kernel, dim3(16),   dim3(256), 0, stream, labels, packed);
    hipLaunchKernelGGL(norm_kernel, dim3(1024), dim3(256), 0, stream, x, norms);
    hipLaunchKernelGGL(main_kernel, dim3(512),  dim3(256), 0, stream, x, packed, norms, acc);
    hipLaunchKernelGGL(final_kernel, dim3(1), dim3(1), 0, stream, acc, out);
}